// Round 3
// baseline (1970.863 us; speedup 1.0000x reference)
//
#include <hip/hip_runtime.h>
#include <hip/hip_fp16.h>
#include <cstdint>

// Problem constants
#define BB 2
#define CC 128
#define IH 800
#define IW 640
#define NN 8192
#define HWp (IH * IW)        // 512000 pixels per batch
#define CE 130               // C + 2 (features + nb x,y)
#define WSL (CE * CC)        // 16640 floats per weight slice [e][o]
#define VPB 16               // vertices per block in fused kernels

// Staggered LDS address for f[e][v] (v in 0..15): scatter writes land 4-way
// max on banks; rows stay 16B-aligned for float4 broadcast reads.
#define FADDR(e, v) (((e) << 4) + ((((e) >> 2)) << 2) + (v))
#define FSZ (FADDR(129, 15) + 1)   // 2208 floats

// ---------------- bilinear helpers ----------------

__device__ __forceinline__ void coords(float gx, float gy, int& xs, int& ys,
                                       float& ax, float& ay) {
  // match reference: clip(((g+1)*0.5)*(dim-1), 0, dim-1); shifting the segment
  // start to min(floor, dim-2) with a in [0,1] reproduces border padding.
  float x = (gx + 1.0f) * 0.5f * (float)(IW - 1);
  x = fminf(fmaxf(x, 0.0f), (float)(IW - 1));
  float y = (gy + 1.0f) * 0.5f * (float)(IH - 1);
  y = fminf(fmaxf(y, 0.0f), (float)(IH - 1));
  xs = min((int)x, IW - 2);
  ys = min((int)y, IH - 2);
  ax = x - (float)xs;
  ay = y - (float)ys;
}

// fp16 HWC gather. Per sample: 2 rows x 2 px x 128 halves = 2 x 512B.
// Lane l: row = l>=32; within row, halves 8*(l&31)..+7 -> x = xs + ((l>>4)&1),
// channels 8*(l&15)..+7. uint4 load = 16B/lane, 1KB/wave per sample.
struct GatH {
  uint4 q;
  float ax, ay;
};

__device__ __forceinline__ GatH gath_issue(const __half* __restrict__ imgT,
                                           int b, float gx, float gy, int l) {
  int xs, ys; float ax, ay;
  coords(gx, gy, xs, ys, ax, ay);
  const __half* base = imgT + ((size_t)b * HWp + (size_t)ys * IW + xs) * CC;
  const __half* row = base + ((l >= 32) ? (size_t)IW * CC : 0);
  GatH g;
  g.q = *(const uint4*)(row + (l & 31) * 8);
  g.ax = ax; g.ay = ay;
  return g;
}

// blend + LDS write: lanes 0..15 hold ch 8m..8m+3 final (write j 0..3),
// lanes 16..31 duplicates (write j 4..7). Lane 32 writes the coord channels.
__device__ __forceinline__ void gath_finish_store(const GatH& g, int l,
                                                  float* __restrict__ f, int v,
                                                  float gx, float gy) {
  float m8[8];
  const __half2* h2 = (const __half2*)&g.q;
#pragma unroll
  for (int w = 0; w < 4; ++w) {
    float2 f2 = __half22float2(h2[w]);
    m8[2 * w] = f2.x; m8[2 * w + 1] = f2.y;
  }
  float my = 1.0f - g.ay, mx = 1.0f - g.ax;
  float r8[8];
#pragma unroll
  for (int j = 0; j < 8; ++j) {
    float oth = __shfl_xor(m8[j], 32);
    float rv = (l < 32) ? (m8[j] * my + oth * g.ay) : (oth * my + m8[j] * g.ay);
    float ox = __shfl_xor(rv, 16);
    r8[j] = (l & 16) ? (ox * mx + rv * g.ax) : (rv * mx + ox * g.ax);
  }
  if (l < 32) {
    int m = l & 15;
    int jb = (l & 16) ? 4 : 0;
#pragma unroll
    for (int j = 0; j < 4; ++j) f[FADDR(8 * m + jb + j, v)] = r8[jb + j];
  }
  if (l == 32) { f[FADDR(128, v)] = gx; f[FADDR(129, v)] = gy; }
}

// CHW (fallback) gather of one channel
__device__ __forceinline__ float gat1_chw(const float* __restrict__ img, int b,
                                          int c, int xs, int ys, float ax, float ay) {
  const float* p = img + ((size_t)(b * CC + c) * IH + ys) * IW + xs;
  float v00 = p[0], v01 = p[1], v10 = p[IW], v11 = p[IW + 1];
  float my = 1.0f - ay, mx = 1.0f - ax;
  return (v00 * mx + v01 * ax) * my + (v10 * mx + v11 * ax) * ay;
}

// ---------------- weight folding ----------------

__global__ void prep1(const float* __restrict__ W_d1, const float* __restrict__ b_d1,
                      const float* __restrict__ W_d2, const float* __restrict__ b_d2,
                      const float* __restrict__ W_c1, const float* __restrict__ b_c1,
                      const float* __restrict__ W_c2, const float* __restrict__ b_c2,
                      float* __restrict__ Wd, float* __restrict__ bdf,
                      float* __restrict__ Wcc, float* __restrict__ bcc) {
  int id = blockIdx.x;
  int e = threadIdx.x;  // 0..129
  if (id < 128) {
    int c = id;
    float acc = 0.0f;
    for (int c2 = 0; c2 < 128; ++c2)
      acc = fmaf(W_d2[c * 128 + c2], W_d1[c2 * CE + e], acc);
    Wd[c * CE + e] = acc;
    if (e == 0) {
      float bb = b_d2[c];
      for (int c2 = 0; c2 < 128; ++c2) bb = fmaf(W_d2[c * 128 + c2], b_d1[c2], bb);
      bdf[c] = bb;
    }
  } else {
    int o = id - 128;
    float acc = 0.0f;
    for (int c2 = 0; c2 < 128; ++c2)
      acc = fmaf(W_c2[o * 128 + c2], W_c1[c2 * CE + e], acc);
    Wcc[o * CE + e] = acc;
    if (e == 0) {
      float bb = b_c2[o];
      for (int c2 = 0; c2 < 128; ++c2) bb = fmaf(W_c2[o * 128 + c2], b_c1[c2], bb);
      bcc[o] = bb;
    }
  }
}

__global__ void prep2(const float* __restrict__ W_sn, const float* __restrict__ b_sn,
                      const float* __restrict__ Wd, const float* __restrict__ bdf,
                      const float* __restrict__ Wcc, const float* __restrict__ bcc,
                      float* __restrict__ Wcen, float* __restrict__ Wnb,
                      float* __restrict__ btot) {
  int eb = blockIdx.x;   // 0..129
  int o = threadIdx.x;   // 0..127
  float acc[9] = {0, 0, 0, 0, 0, 0, 0, 0, 0};
  float bacc = 0.0f;
  for (int c = 0; c < 128; ++c) {
    float wd = Wd[c * CE + eb];
    float bd = bdf[c];
    const float* sn = W_sn + (size_t)o * 1152 + c * 9;
    float ssum = 0.0f;
#pragma unroll
    for (int k = 0; k < 9; ++k) {
      float s = sn[k];
      acc[k] = fmaf(s, wd, acc[k]);
      ssum += s;
    }
    bacc = fmaf(ssum, bd, bacc);
  }
  float sum18 = 0.0f;
#pragma unroll
  for (int k = 1; k < 9; ++k) {
    Wnb[(size_t)(k - 1) * WSL + eb * 128 + o] = acc[k];
    sum18 += acc[k];
  }
  Wcen[eb * 128 + o] = Wcc[o * CE + eb] - sum18;
  if (eb == 0) btot[o] = bcc[o] + bacc + b_sn[o];
}

// -------- prep_img: (B,C,H,W) fp32 -> (B,HW,C) fp16  +  SDIMG (B,HW,18) fp32
// SDIMG[j] = sum_c W_sd[j,c]*img[c] -- bilinear commutes with the 1x1 conv,
// so offsets sampled from SDIMG are fp32-exact (no fp16 amplification).

__global__ __launch_bounds__(256) void prep_img(const float* __restrict__ img,
                                                const float* __restrict__ W_sd,
                                                __half* __restrict__ imgT,
                                                float* __restrict__ sdimg) {
  __shared__ float tile[128][69];  // stride 69: load 2-way, reads ~4-way max
  int b = blockIdx.y;
  size_t p0 = (size_t)blockIdx.x * 64;
  int t = threadIdx.x;

  // read: float4 along pixels, 256B segments per channel
  int pq = t & 15, cr = t >> 4;
  float4 vr[8];
#pragma unroll
  for (int i = 0; i < 8; ++i) {
    int c = cr + (i << 4);
    vr[i] = *(const float4*)(img + (size_t)(b * CC + c) * HWp + p0 + pq * 4);
  }
#pragma unroll
  for (int i = 0; i < 8; ++i) {
    int c = cr + (i << 4);
    tile[c][pq * 4 + 0] = vr[i].x;
    tile[c][pq * 4 + 1] = vr[i].y;
    tile[c][pq * 4 + 2] = vr[i].z;
    tile[c][pq * 4 + 3] = vr[i].w;
  }
  __syncthreads();

  // fp16 write: lane covers 8 channels of one pixel; wave = 4 px = 1KB contig
  int c8 = (t & 15) * 8, pw0 = t >> 4;
#pragma unroll
  for (int r = 0; r < 4; ++r) {
    int p = pw0 + (r << 4);
    uint4 q;
    __half2* h2 = (__half2*)&q;
#pragma unroll
    for (int w = 0; w < 4; ++w)
      h2[w] = __floats2half2_rn(tile[c8 + 2 * w][p], tile[c8 + 2 * w + 1][p]);
    *(uint4*)(imgT + ((size_t)b * HWp + p0 + p) * CC + c8) = q;
  }

  // SDIMG: wave-uniform j-set -> W_sd reads become scalar loads
  int px = t & 63;
  int jg = __builtin_amdgcn_readfirstlane(t >> 6);
  int jbase = (jg < 2) ? jg * 5 : 10 + (jg - 2) * 4;
  int jn = (jg < 2) ? 5 : 4;
  float acc[5] = {0, 0, 0, 0, 0};
  for (int c = 0; c < 128; ++c) {
    float v = tile[c][px];
    for (int m = 0; m < jn; ++m)
      acc[m] = fmaf(W_sd[(jbase + m) * 128 + c], v, acc[m]);
  }
  for (int m = 0; m < jn; ++m)
    sdimg[((size_t)b * HWp + p0 + px) * 18 + jbase + m] = acc[m];
}

// ---------------- fused HWC: sd-sample + 9 gathers + folded GEMM ----------
// Thread map for GEMM: l=t&63 -> o in {l, l+64}; vg=(t>>6)&1 -> v-half;
// hs=t>>7 -> e-half. Halves broadcast ds_read count vs o-per-thread map.

__device__ __forceinline__ void gemm_slice(const float* __restrict__ fb,
                                           const float* __restrict__ Ws,
                                           int l, int eb, int vbase,
                                           float acc0[8], float acc1[8]) {
  for (int e = eb; e < eb + 65; ++e) {
    float w0 = Ws[e * 128 + l];
    float w1 = Ws[e * 128 + 64 + l];
    const float4* fp = (const float4*)&fb[FADDR(e, vbase)];
    float4 fa = fp[0], fb4 = fp[1];
    acc0[0] = fmaf(fa.x, w0, acc0[0]);  acc1[0] = fmaf(fa.x, w1, acc1[0]);
    acc0[1] = fmaf(fa.y, w0, acc0[1]);  acc1[1] = fmaf(fa.y, w1, acc1[1]);
    acc0[2] = fmaf(fa.z, w0, acc0[2]);  acc1[2] = fmaf(fa.z, w1, acc1[2]);
    acc0[3] = fmaf(fa.w, w0, acc0[3]);  acc1[3] = fmaf(fa.w, w1, acc1[3]);
    acc0[4] = fmaf(fb4.x, w0, acc0[4]); acc1[4] = fmaf(fb4.x, w1, acc1[4]);
    acc0[5] = fmaf(fb4.y, w0, acc0[5]); acc1[5] = fmaf(fb4.y, w1, acc1[5]);
    acc0[6] = fmaf(fb4.z, w0, acc0[6]); acc1[6] = fmaf(fb4.z, w1, acc1[6]);
    acc0[7] = fmaf(fb4.w, w0, acc0[7]); acc1[7] = fmaf(fb4.w, w1, acc1[7]);
  }
}

__global__ __launch_bounds__(256) void fused_hwc(
    const __half* __restrict__ imgT, const float* __restrict__ sdimg,
    const float* __restrict__ verts, const float* __restrict__ b_sd,
    const float* __restrict__ Wcen, const float* __restrict__ Wnb,
    const float* __restrict__ btot, float* __restrict__ out) {
  __shared__ __align__(16) float f0[FSZ], f1[FSZ];
  __shared__ float sdl[VPB][18];
  __shared__ float nbc[VPB][16];
  __shared__ float red[128][17];
  int t = threadIdx.x;
  int v0 = blockIdx.x * VPB;
  int wv = t >> 6, l = t & 63;
  int vg = (t >> 6) & 1, hs = t >> 7;
  int eb = hs * 65, vbase = vg * 8;
  float acc0[8] = {}, acc1[8] = {};

  // issue center gathers first (longest latency)
  GatH g[4]; float gxy[4][2];
#pragma unroll
  for (int s = 0; s < 4; ++s) {
    int vid = v0 + wv * 4 + s;
    float gx = verts[vid * 2], gy = verts[vid * 2 + 1];
    gxy[s][0] = gx; gxy[s][1] = gy;
    g[s] = gath_issue(imgT, vid >> 13, gx, gy, l);
  }

  // offsets from SDIMG (fp32-exact)
  for (int idx = t; idx < VPB * 18; idx += 256) {
    int v = idx / 18, j = idx - v * 18;
    int vid = v0 + v, b = vid >> 13;
    float gx = verts[vid * 2], gy = verts[vid * 2 + 1];
    int xs, ys; float ax, ay;
    coords(gx, gy, xs, ys, ax, ay);
    const float* sp = sdimg + ((size_t)b * HWp + (size_t)ys * IW + xs) * 18 + j;
    float v00 = sp[0], v01 = sp[18];
    float v10 = sp[(size_t)IW * 18], v11 = sp[(size_t)IW * 18 + 18];
    float my = 1.0f - ay, mx = 1.0f - ax;
    sdl[v][j] = (v00 * mx + v01 * ax) * my + (v10 * mx + v11 * ax) * ay + b_sd[j];
  }
  __syncthreads();
  {
    int v = t >> 4, j2 = t & 15;
    int vid = v0 + v;
    nbc[v][j2] = verts[vid * 2 + (j2 & 1)] + sdl[v][2 + j2];
  }
  // finish center -> f0
#pragma unroll
  for (int s = 0; s < 4; ++s)
    gath_finish_store(g[s], l, f0, wv * 4 + s, gxy[s][0], gxy[s][1]);
  __syncthreads();

  // pipelined slices: issue(s+1) -> GEMM(s) -> finish(s+1) -> barrier
  const float* fb = f0;
  for (int s = 0; s < 9; ++s) {
    float* fnext = (s & 1) ? f0 : f1;
    if (s < 8) {
#pragma unroll
      for (int q = 0; q < 4; ++q) {
        int v = wv * 4 + q, vid = v0 + v;
        float gx = nbc[v][2 * s], gy = nbc[v][2 * s + 1];
        gxy[q][0] = gx; gxy[q][1] = gy;
        g[q] = gath_issue(imgT, vid >> 13, gx, gy, l);
      }
    }
    const float* Ws = (s == 0) ? Wcen : Wnb + (size_t)(s - 1) * WSL;
    gemm_slice(fb, Ws, l, eb, vbase, acc0, acc1);
    if (s < 8) {
#pragma unroll
      for (int q = 0; q < 4; ++q)
        gath_finish_store(g[q], l, fnext, wv * 4 + q, gxy[q][0], gxy[q][1]);
    }
    __syncthreads();
    fb = fnext;
  }

  // reduce e-halves and store
  if (hs) {
#pragma unroll
    for (int j = 0; j < 8; ++j) {
      red[l][vbase + j] = acc0[j];
      red[l + 64][vbase + j] = acc1[j];
    }
  }
  __syncthreads();
  if (!hs) {
    float b0 = btot[l], b1 = btot[l + 64];
#pragma unroll
    for (int j = 0; j < 8; ++j) {
      out[(size_t)(v0 + vbase + j) * CC + l]      = acc0[j] + red[l][vbase + j] + b0;
      out[(size_t)(v0 + vbase + j) * CC + l + 64] = acc1[j] + red[l + 64][vbase + j] + b1;
    }
  }
}

// ---------------- CHW fallback (fp32, sd from features) ----------------

__global__ __launch_bounds__(256) void fused_chw(
    const float* __restrict__ img, const float* __restrict__ verts,
    const float* __restrict__ W_sd, const float* __restrict__ b_sd,
    const float* __restrict__ Wcen, const float* __restrict__ Wnb,
    const float* __restrict__ btot, float* __restrict__ out) {
  __shared__ __align__(16) float f[FSZ];
  __shared__ float sdl[VPB][18];
  __shared__ float nbc[VPB][16];
  __shared__ float red[128][17];
  int t = threadIdx.x;
  int o = t & 127, hs = t >> 7;
  int e0 = hs * 65;
  int v0 = blockIdx.x * VPB;
  int wv = t >> 6, l = t & 63;
  float acc[VPB] = {};

  for (int s = 0; s < 4; ++s) {
    int v = wv * 4 + s, vid = v0 + v, b = vid >> 13;
    float gx = verts[vid * 2], gy = verts[vid * 2 + 1];
    int xs, ys; float ax, ay;
    coords(gx, gy, xs, ys, ax, ay);
    f[FADDR(l, v)] = gat1_chw(img, b, l, xs, ys, ax, ay);
    f[FADDR(l + 64, v)] = gat1_chw(img, b, l + 64, xs, ys, ax, ay);
    if (l == 0) { f[FADDR(128, v)] = gx; f[FADDR(129, v)] = gy; }
  }
  __syncthreads();

  for (int idx = t; idx < VPB * 18; idx += 256) {
    int v = idx / 18, oo = idx - v * 18;
    float a = b_sd[oo];
    for (int c = 0; c < 128; ++c)
      a = fmaf(W_sd[oo * 128 + c], f[FADDR(c, v)], a);
    sdl[v][oo] = a;
  }

  {
    const float* Ws = Wcen;
    for (int e = e0; e < e0 + 65; ++e) {
      float w = Ws[e * 128 + o];
      const float4* fp = (const float4*)&f[FADDR(e, 0)];
      float4 fa = fp[0], fb = fp[1], fc = fp[2], fd = fp[3];
      acc[0]  = fmaf(fa.x, w, acc[0]);  acc[1]  = fmaf(fa.y, w, acc[1]);
      acc[2]  = fmaf(fa.z, w, acc[2]);  acc[3]  = fmaf(fa.w, w, acc[3]);
      acc[4]  = fmaf(fb.x, w, acc[4]);  acc[5]  = fmaf(fb.y, w, acc[5]);
      acc[6]  = fmaf(fb.z, w, acc[6]);  acc[7]  = fmaf(fb.w, w, acc[7]);
      acc[8]  = fmaf(fc.x, w, acc[8]);  acc[9]  = fmaf(fc.y, w, acc[9]);
      acc[10] = fmaf(fc.z, w, acc[10]); acc[11] = fmaf(fc.w, w, acc[11]);
      acc[12] = fmaf(fd.x, w, acc[12]); acc[13] = fmaf(fd.y, w, acc[13]);
      acc[14] = fmaf(fd.z, w, acc[14]); acc[15] = fmaf(fd.w, w, acc[15]);
    }
  }
  __syncthreads();
  {
    int v = t >> 4, j = t & 15, k = (j >> 1) + 1, comp = j & 1;
    int vid = v0 + v;
    nbc[v][j] = verts[vid * 2 + comp] + sdl[v][k * 2 + comp];
  }
  __syncthreads();

  for (int k = 0; k < 8; ++k) {
    for (int s = 0; s < 4; ++s) {
      int v = wv * 4 + s, vid = v0 + v, b = vid >> 13;
      float gx = nbc[v][k * 2], gy = nbc[v][k * 2 + 1];
      int xs, ys; float ax, ay;
      coords(gx, gy, xs, ys, ax, ay);
      f[FADDR(l, v)] = gat1_chw(img, b, l, xs, ys, ax, ay);
      f[FADDR(l + 64, v)] = gat1_chw(img, b, l + 64, xs, ys, ax, ay);
      if (l == 0) { f[FADDR(128, v)] = gx; f[FADDR(129, v)] = gy; }
    }
    __syncthreads();
    const float* Ws = Wnb + (size_t)k * WSL;
    for (int e = e0; e < e0 + 65; ++e) {
      float w = Ws[e * 128 + o];
      const float4* fp = (const float4*)&f[FADDR(e, 0)];
      float4 fa = fp[0], fb = fp[1], fc = fp[2], fd = fp[3];
      acc[0]  = fmaf(fa.x, w, acc[0]);  acc[1]  = fmaf(fa.y, w, acc[1]);
      acc[2]  = fmaf(fa.z, w, acc[2]);  acc[3]  = fmaf(fa.w, w, acc[3]);
      acc[4]  = fmaf(fb.x, w, acc[4]);  acc[5]  = fmaf(fb.y, w, acc[5]);
      acc[6]  = fmaf(fb.z, w, acc[6]);  acc[7]  = fmaf(fb.w, w, acc[7]);
      acc[8]  = fmaf(fc.x, w, acc[8]);  acc[9]  = fmaf(fc.y, w, acc[9]);
      acc[10] = fmaf(fc.z, w, acc[10]); acc[11] = fmaf(fc.w, w, acc[11]);
      acc[12] = fmaf(fd.x, w, acc[12]); acc[13] = fmaf(fd.y, w, acc[13]);
      acc[14] = fmaf(fd.z, w, acc[14]); acc[15] = fmaf(fd.w, w, acc[15]);
    }
    __syncthreads();
  }

  if (hs) {
#pragma unroll
    for (int j = 0; j < VPB; ++j) red[o][j & 15] = acc[j];
  }
  __syncthreads();
  if (!hs) {
    float bt = btot[o];
#pragma unroll
    for (int j = 0; j < VPB; ++j)
      out[(size_t)(v0 + j) * CC + o] = acc[j] + red[o][j & 15] + bt;
  }
}

// ---------------- launch ----------------

extern "C" void kernel_launch(void* const* d_in, const int* in_sizes, int n_in,
                              void* d_out, int out_size, void* d_ws, size_t ws_size,
                              hipStream_t stream) {
  const float* img   = (const float*)d_in[0];
  const float* verts = (const float*)d_in[1];
  const float* W_sd  = (const float*)d_in[2];
  const float* b_sd  = (const float*)d_in[3];
  const float* W_d1  = (const float*)d_in[4];
  const float* b_d1  = (const float*)d_in[5];
  const float* W_d2  = (const float*)d_in[6];
  const float* b_d2  = (const float*)d_in[7];
  const float* W_sn  = (const float*)d_in[8];
  const float* b_sn  = (const float*)d_in[9];
  const float* W_c1  = (const float*)d_in[10];
  const float* b_c1  = (const float*)d_in[11];
  const float* W_c2  = (const float*)d_in[12];
  const float* b_c2  = (const float*)d_in[13];
  float* out = (float*)d_out;

  const size_t imgT_bytes = (size_t)BB * HWp * CC * 2;       // 262 MB
  const size_t sdimg_fl   = (size_t)BB * HWp * 18;           // 73.7 MB
  const size_t wt_fl      = 11 * (size_t)WSL + 384;
  bool hwc = ws_size >= imgT_bytes + (sdimg_fl + wt_fl) * sizeof(float);

  char* base = (char*)d_ws;
  __half* imgT = nullptr;
  float* sdimg = nullptr;
  if (hwc) {
    imgT = (__half*)base;
    sdimg = (float*)(base + imgT_bytes);
    base = (char*)(sdimg + sdimg_fl);
  }
  float* fbase = (float*)base;
  float* Wd   = fbase;  fbase += WSL;
  float* bdf  = fbase;  fbase += 128;
  float* Wcc  = fbase;  fbase += WSL;
  float* bcc  = fbase;  fbase += 128;
  float* Wcen = fbase;  fbase += WSL;
  float* Wnb  = fbase;  fbase += 8 * WSL;
  float* btot = fbase;

  prep1<<<256, 130, 0, stream>>>(W_d1, b_d1, W_d2, b_d2, W_c1, b_c1, W_c2, b_c2,
                                 Wd, bdf, Wcc, bcc);
  prep2<<<130, 128, 0, stream>>>(W_sn, b_sn, Wd, bdf, Wcc, bcc, Wcen, Wnb, btot);

  if (hwc) {
    prep_img<<<dim3(HWp / 64, BB), 256, 0, stream>>>(img, W_sd, imgT, sdimg);
    fused_hwc<<<BB * NN / VPB, 256, 0, stream>>>(imgT, sdimg, verts, b_sd,
                                                 Wcen, Wnb, btot, out);
  } else {
    fused_chw<<<BB * NN / VPB, 256, 0, stream>>>(img, verts, W_sd, b_sd,
                                                 Wcen, Wnb, btot, out);
  }
}